// Round 17
// baseline (124.567 us; speedup 1.0000x reference)
//
#include <hip/hip_runtime.h>
#include <hip/hip_bf16.h>
#include <cstdint>
#include <cstddef>

typedef __bf16 bf16x8 __attribute__((ext_vector_type(8)));
typedef float f32x4 __attribute__((ext_vector_type(4)));
typedef float f32x16 __attribute__((ext_vector_type(16)));
typedef unsigned int u32x4 __attribute__((ext_vector_type(4)));
typedef unsigned int u32x2 __attribute__((ext_vector_type(2)));

#define SCALE_LOG2E 0.25503513f   // (1/sqrt(32)) * log2(e)
#define LOG2E 1.4426950408889634f

union U16x8 {
  u32x4 u;
  bf16x8 b;
  unsigned short s[8];
  ushort4 q[2];
};

__device__ __forceinline__ unsigned short f2bf(float f) {
  union { float f; unsigned u; } v;
  v.f = f;
  unsigned r = v.u + 0x7FFFu + ((v.u >> 16) & 1u);
  return (unsigned short)(r >> 16);
}

__device__ __forceinline__ unsigned pack2(float a, float b) {
  __hip_bfloat162 t = __float22bfloat162_rn(make_float2(a, b));
  return *reinterpret_cast<unsigned*>(&t);  // low16 = bf(a), high16 = bf(b)
}

// ---------------- merged: weight prep (blocks 0..2050) + LayerNorm1 (blocks 2051..4098) ----------------
__global__ __launch_bounds__(256) void prep_ln_kernel(
    const float* __restrict__ Wqkv, const float* __restrict__ Wout,
    const float* __restrict__ Wf1, const float* __restrict__ Wf2,
    const float* __restrict__ bqkv,
    const float* __restrict__ x, const float* __restrict__ gw, const float* __restrict__ bw,
    unsigned short* __restrict__ qkv_t, unsigned short* __restrict__ out_t,
    unsigned short* __restrict__ f1_t, unsigned short* __restrict__ f2_t,
    float* __restrict__ bqkv_s, unsigned short* __restrict__ ln_out) {
  const int blk = blockIdx.x;
  if (blk >= 2051) {
    const int row = (blk - 2051) * 4 + (threadIdx.x >> 6);
    const int lane = threadIdx.x & 63;
    const float4 v = *reinterpret_cast<const float4*>(x + (size_t)row * 256 + lane * 4);
    float s = v.x + v.y + v.z + v.w;
    float s2 = v.x * v.x + v.y * v.y + v.z * v.z + v.w * v.w;
#pragma unroll
    for (int m = 1; m < 64; m <<= 1) {
      s += __shfl_xor(s, m);
      s2 += __shfl_xor(s2, m);
    }
    const float mean = s * (1.f / 256.f);
    const float var = s2 * (1.f / 256.f) - mean * mean;
    const float rstd = rsqrtf(var + 1e-5f);
    const float4 gg = *reinterpret_cast<const float4*>(gw + lane * 4);
    const float4 bb = *reinterpret_cast<const float4*>(bw + lane * 4);
    ushort4 o;
    o.x = f2bf((v.x - mean) * rstd * gg.x + bb.x);
    o.y = f2bf((v.y - mean) * rstd * gg.y + bb.y);
    o.z = f2bf((v.z - mean) * rstd * gg.z + bb.z);
    o.w = f2bf((v.w - mean) * rstd * gg.w + bb.w);
    *reinterpret_cast<ushort4*>(ln_out + (size_t)row * 256 + lane * 4) = o;
    return;
  }
  int i = blk * 256 + threadIdx.x;
  if (i < 768 * 256) {
    int n = i >> 8, k = i & 255;
    float v = Wqkv[k * 768 + n];
    if (n < 256) v *= SCALE_LOG2E;  // fold softmax scale * log2e into Q
    qkv_t[i] = f2bf(v);
    return;
  }
  i -= 768 * 256;
  if (i < 256 * 256) { int n = i >> 8, k = i & 255; out_t[i] = f2bf(Wout[k * 256 + n]); return; }
  i -= 256 * 256;
  if (i < 512 * 256) { int n = i >> 8, k = i & 255; f1_t[i] = f2bf(Wf1[k * 512 + n]); return; }
  i -= 512 * 256;
  if (i < 256 * 512) { int n = i >> 9, k = i & 511; f2_t[i] = f2bf(Wf2[k * 256 + n]); return; }
  i -= 256 * 512;
  if (i < 768) bqkv_s[i] = bqkv[i] * (i < 256 ? SCALE_LOG2E : 1.0f);
}

// ---------------- LayerNorm (f32 in -> bf16 out), 1 wave per 256-wide row ----------------
__global__ __launch_bounds__(256) void ln_kernel(
    const float* __restrict__ x, const float* __restrict__ gw, const float* __restrict__ bw,
    unsigned short* __restrict__ out) {
  const int row = blockIdx.x * 4 + (threadIdx.x >> 6);
  const int lane = threadIdx.x & 63;
  const float4 v = *reinterpret_cast<const float4*>(x + (size_t)row * 256 + lane * 4);
  float s = v.x + v.y + v.z + v.w;
  float s2 = v.x * v.x + v.y * v.y + v.z * v.z + v.w * v.w;
#pragma unroll
  for (int m = 1; m < 64; m <<= 1) {
    s += __shfl_xor(s, m);
    s2 += __shfl_xor(s2, m);
  }
  const float mean = s * (1.f / 256.f);
  const float var = s2 * (1.f / 256.f) - mean * mean;
  const float rstd = rsqrtf(var + 1e-5f);
  const float4 gg = *reinterpret_cast<const float4*>(gw + lane * 4);
  const float4 bb = *reinterpret_cast<const float4*>(bw + lane * 4);
  ushort4 o;
  o.x = f2bf((v.x - mean) * rstd * gg.x + bb.x);
  o.y = f2bf((v.y - mean) * rstd * gg.y + bb.y);
  o.z = f2bf((v.z - mean) * rstd * gg.z + bb.z);
  o.w = f2bf((v.w - mean) * rstd * gg.w + bb.w);
  *reinterpret_cast<ushort4*>(out + (size_t)row * 256 + lane * 4) = o;
}

// ---------------- direct-global MFMA GEMM, 128x64 tile, pinned 1-ahead prefetch ----------------
template <int EPI, int K, int N>
__global__ __launch_bounds__(256) void gemm_kernel(
    const unsigned short* __restrict__ A, const unsigned short* __restrict__ Wt,
    const float* __restrict__ bias, const float* __restrict__ res, void* __restrict__ outp) {
  const int w = threadIdx.x >> 6;
  const int lane = threadIdx.x & 63;
  const int l15 = lane & 15;
  const int g = lane >> 4;
  const int m0 = blockIdx.x * 128 + w * 32;
  const int n0 = blockIdx.y * 64;
  constexpr int KI = K / 32;

  const unsigned short* a0p = A + (size_t)(m0 + l15) * K + g * 8;
  const unsigned short* a1p = A + (size_t)(m0 + 16 + l15) * K + g * 8;
  const unsigned short* wp = Wt + (size_t)(n0 + l15) * K + g * 8;

  f32x4 acc[2][4];
#pragma unroll
  for (int mf = 0; mf < 2; ++mf)
#pragma unroll
    for (int nf = 0; nf < 4; ++nf) acc[mf][nf] = f32x4{0.f, 0.f, 0.f, 0.f};

  U16x8 a[2][2], bfr[2][4];

#define GEMM_LOAD(kk, buf)                                                                  \
  do {                                                                                      \
    a[buf][0].u = *reinterpret_cast<const u32x4*>(a0p + (kk) * 32);                         \
    a[buf][1].u = *reinterpret_cast<const u32x4*>(a1p + (kk) * 32);                         \
    bfr[buf][0].u = *reinterpret_cast<const u32x4*>(wp + (size_t)0 * 16 * K + (kk) * 32);   \
    bfr[buf][1].u = *reinterpret_cast<const u32x4*>(wp + (size_t)1 * 16 * K + (kk) * 32);   \
    bfr[buf][2].u = *reinterpret_cast<const u32x4*>(wp + (size_t)2 * 16 * K + (kk) * 32);   \
    bfr[buf][3].u = *reinterpret_cast<const u32x4*>(wp + (size_t)3 * 16 * K + (kk) * 32);   \
  } while (0)

  GEMM_LOAD(0, 0);
  __builtin_amdgcn_sched_barrier(0);

#pragma unroll
  for (int kk = 0; kk < KI; ++kk) {
    if (kk + 1 < KI) GEMM_LOAD(kk + 1, (kk + 1) & 1);
    __builtin_amdgcn_sched_barrier(0);
    const int buf = kk & 1;
#pragma unroll
    for (int mf = 0; mf < 2; ++mf)
#pragma unroll
      for (int nf = 0; nf < 4; ++nf)
        acc[mf][nf] = __builtin_amdgcn_mfma_f32_16x16x32_bf16(a[buf][mf].b, bfr[buf][nf].b, acc[mf][nf], 0, 0, 0);
  }
#undef GEMM_LOAD

#pragma unroll
  for (int mf = 0; mf < 2; ++mf)
#pragma unroll
    for (int nf = 0; nf < 4; ++nf)
#pragma unroll
      for (int r = 0; r < 4; ++r) {
        const int m = m0 + mf * 16 + g * 4 + r;
        const int n = n0 + nf * 16 + l15;
        float v = acc[mf][nf][r] + bias[n];
        if constexpr (EPI == 1) {
          v += res[(size_t)m * 256 + n];
          reinterpret_cast<float*>(outp)[(size_t)m * 256 + n] = v;
        } else if constexpr (EPI == 2) {
          v = 0.5f * v * (1.0f + erff(v * 0.70710678118654752f));
          reinterpret_cast<unsigned short*>(outp)[(size_t)m * N + n] = f2bf(v);
        } else {
          reinterpret_cast<unsigned short*>(outp)[(size_t)m * N + n] = f2bf(v);
        }
      }
}

// ---------------- fused QKV GEMM: Q -> qbuf[c][256], K/V -> frag-contiguous kf/vf ----------------
__global__ __launch_bounds__(256) void qkv_gemm(
    const unsigned short* __restrict__ A, const unsigned short* __restrict__ Wt,
    const float* __restrict__ bias,
    unsigned short* __restrict__ qbuf, unsigned short* __restrict__ kf,
    unsigned short* __restrict__ vf) {
  __shared__ unsigned short tile[128][72];  // row stride 144 B (16B-aligned rows)
  const int w = threadIdx.x >> 6;
  const int lane = threadIdx.x & 63;
  const int l15 = lane & 15, g = lane >> 4;
  const int l31 = lane & 31, hi = lane >> 5;
  const int mb = blockIdx.x, nb = blockIdx.y;
  const int m0 = mb * 128 + w * 32;
  const int n0 = nb * 64;
  constexpr int K = 256;
  constexpr int KI = 8;

  const unsigned short* a0p = A + (size_t)(m0 + l15) * K + g * 8;
  const unsigned short* a1p = A + (size_t)(m0 + 16 + l15) * K + g * 8;
  const unsigned short* wp = Wt + (size_t)(n0 + l15) * K + g * 8;

  f32x4 acc[2][4];
#pragma unroll
  for (int mf = 0; mf < 2; ++mf)
#pragma unroll
    for (int nf = 0; nf < 4; ++nf) acc[mf][nf] = f32x4{0.f, 0.f, 0.f, 0.f};

  U16x8 a[2][2], bfr[2][4];

#define QKV_LOAD(kk, buf)                                                                   \
  do {                                                                                      \
    a[buf][0].u = *reinterpret_cast<const u32x4*>(a0p + (kk) * 32);                         \
    a[buf][1].u = *reinterpret_cast<const u32x4*>(a1p + (kk) * 32);                         \
    bfr[buf][0].u = *reinterpret_cast<const u32x4*>(wp + (size_t)0 * 16 * K + (kk) * 32);   \
    bfr[buf][1].u = *reinterpret_cast<const u32x4*>(wp + (size_t)1 * 16 * K + (kk) * 32);   \
    bfr[buf][2].u = *reinterpret_cast<const u32x4*>(wp + (size_t)2 * 16 * K + (kk) * 32);   \
    bfr[buf][3].u = *reinterpret_cast<const u32x4*>(wp + (size_t)3 * 16 * K + (kk) * 32);   \
  } while (0)

  QKV_LOAD(0, 0);
  __builtin_amdgcn_sched_barrier(0);

#pragma unroll
  for (int kk = 0; kk < KI; ++kk) {
    if (kk + 1 < KI) QKV_LOAD(kk + 1, (kk + 1) & 1);
    __builtin_amdgcn_sched_barrier(0);
    const int buf = kk & 1;
#pragma unroll
    for (int mf = 0; mf < 2; ++mf)
#pragma unroll
      for (int nf = 0; nf < 4; ++nf)
        acc[mf][nf] = __builtin_amdgcn_mfma_f32_16x16x32_bf16(a[buf][mf].b, bfr[buf][nf].b, acc[mf][nf], 0, 0, 0);
  }
#undef QKV_LOAD

  if (nb < 4) {
    // Q region: row-major qbuf [8192][256]
#pragma unroll
    for (int mf = 0; mf < 2; ++mf)
#pragma unroll
      for (int nf = 0; nf < 4; ++nf)
#pragma unroll
        for (int r = 0; r < 4; ++r) {
          const int m = m0 + mf * 16 + g * 4 + r;
          const int n = n0 + nf * 16 + l15;
          qbuf[(size_t)m * 256 + n] = f2bf(acc[mf][nf][r] + bias[n]);
        }
    return;
  }

  // K/V region: stage bf16 tile [c_local][n_local] in LDS
#pragma unroll
  for (int mf = 0; mf < 2; ++mf)
#pragma unroll
    for (int nf = 0; nf < 4; ++nf)
#pragma unroll
      for (int r = 0; r < 4; ++r) {
        const int n = n0 + nf * 16 + l15;
        tile[w * 32 + mf * 16 + g * 4 + r][nf * 16 + l15] = f2bf(acc[mf][nf][r] + bias[n]);
      }
  __syncthreads();

  const int b = mb >> 4;
  const int Sg = (mb & 15) * 4 + w;  // wave w owns c-subtile w of this 128-row tile

  if (nb < 8) {
    // K: kf chunk (b,h,Sg,d2)[lane]: K[c=Sg*32+l31][dk=d2*16+hi*8+j]
    const int hb = 2 * (nb - 4);
#pragma unroll
    for (int hd2 = 0; hd2 < 4; ++hd2) {
      const int hl = hd2 >> 1, d2 = hd2 & 1;
      U16x8 vv;
      vv.q[0] = *reinterpret_cast<const ushort4*>(&tile[w * 32 + l31][hl * 32 + d2 * 16 + hi * 8]);
      vv.q[1] = *reinterpret_cast<const ushort4*>(&tile[w * 32 + l31][hl * 32 + d2 * 16 + hi * 8 + 4]);
      const size_t chunk = ((size_t)(b * 8 + hb + hl) * 64 + Sg) * 2 + d2;
      *reinterpret_cast<u32x4*>(kf + chunk * 512 + lane * 8) = vv.u;
    }
  } else {
    // V: vf chunk (b,h,Sg,kd2)[lane]: V[c=Sg*32+kd2*16+hi*8+j][d=l31] (transpose read)
    const int hb = 2 * (nb - 8);
#pragma unroll
    for (int hd2 = 0; hd2 < 4; ++hd2) {
      const int hl = hd2 >> 1, kd2 = hd2 & 1;
      U16x8 vv;
#pragma unroll
      for (int j = 0; j < 8; ++j)
        vv.s[j] = tile[w * 32 + kd2 * 16 + hi * 8 + j][hl * 32 + l31];
      const size_t chunk = ((size_t)(b * 8 + hb + hl) * 64 + Sg) * 2 + kd2;
      *reinterpret_cast<u32x4*>(vf + chunk * 512 + lane * 8) = vv.u;
    }
  }
}

// ---------------- flash attention (R13 structure, 2-deep adj buffers: 67.6 KB -> 2 blocks/CU) ----------------
// 16 waves = 8 heads x 2 KV-halves. S^T[k][q] = mfma32(K, Q^T), exp2 softmax (no max
// tracking; scores bounded), P exchange via permlane32_swap, O^T += mfma32(V^T, P).
// K/V frags pinned ONE sub ahead with sched_barrier(0): only 2 sub-buffers live at once
// (R13's exact body, measured 64 VGPR). Buffer depth 3->2 halves LDS so 2 blocks/CU can
// co-schedule (the VGPR-neutral occupancy lever; R15's kvq split drifted to 68 VGPR).
__global__ __launch_bounds__(1024) void attn_kernel(
    const unsigned short* __restrict__ qbuf,
    const unsigned short* __restrict__ kf, const unsigned short* __restrict__ vf,
    const float* __restrict__ adj, unsigned short* __restrict__ out) {
  __shared__ __align__(16) float adj_lds[2][2][32 * 132];  // 67584 B
  const int w = threadIdx.x >> 6;
  const int lane = threadIdx.x & 63;
  const int l31 = lane & 31;
  const int hi = lane >> 5;
  const int h = w & 7;
  const int kvh = w >> 3;
  const int q0 = blockIdx.x * 32;
  const int b = blockIdx.y;

  const float* agbase = adj + (size_t)(b * 2048 + q0 + 4 * h) * 2048 + kvh * 1024 + lane;

  // Q B-frags (persistent, pre-scaled by scale*log2e): B[kk=hi*8+j][q=l31]
  U16x8 qb[2];
#pragma unroll
  for (int d = 0; d < 2; ++d)
    qb[d].u = *reinterpret_cast<const u32x4*>(
        qbuf + (size_t)(b * 2048 + q0 + l31) * 256 + h * 32 + d * 16 + hi * 8);

  const unsigned short* kfh = kf + (size_t)(b * 8 + h) * 65536;
  const unsigned short* vfh = vf + (size_t)(b * 8 + h) * 65536;

  f32x16 o;
#pragma unroll
  for (int i = 0; i < 16; ++i) o[i] = 0.f;
  float lrun = 0.f;

  // prologue: DMA adj stages 0,1 (8 dword-DMAs per wave per stage)
#pragma unroll
  for (int pt = 0; pt < 2; ++pt)
#pragma unroll
    for (int r = 0; r < 4; ++r)
#pragma unroll
      for (int half = 0; half < 2; ++half)
        __builtin_amdgcn_global_load_lds(
            (const __attribute__((address_space(1))) unsigned int*)(agbase + (size_t)r * 2048 + pt * 128 + half * 64),
            (__attribute__((address_space(3))) unsigned int*)(&adj_lds[kvh][pt][(4 * h + r) * 132 + half * 64]),
            4, 0, 0);

#pragma unroll 1
  for (int t = 0; t < 8; ++t) {
    const float* buf = adj_lds[kvh][t & 1];
    // stage(t) complete when <=8 of our DMA loads outstanding (stage t+1 in flight)
    if (t < 7) asm volatile("s_waitcnt vmcnt(8)" ::: "memory");
    else       asm volatile("s_waitcnt vmcnt(0)" ::: "memory");
    __builtin_amdgcn_s_barrier();
    __builtin_amdgcn_sched_barrier(0);

    const int S0 = kvh * 32 + t * 4;  // first 32-kv subtile of this tile

    // K/V frags, software-pipelined one sub ahead (full unroll -> static indices)
    U16x8 kA[4][2], vA[4][2];
    kA[0][0].u = *reinterpret_cast<const u32x4*>(kfh + ((size_t)(S0 * 2 + 0) * 64 + lane) * 8);
    kA[0][1].u = *reinterpret_cast<const u32x4*>(kfh + ((size_t)(S0 * 2 + 1) * 64 + lane) * 8);
    vA[0][0].u = *reinterpret_cast<const u32x4*>(vfh + ((size_t)(S0 * 2 + 0) * 64 + lane) * 8);
    vA[0][1].u = *reinterpret_cast<const u32x4*>(vfh + ((size_t)(S0 * 2 + 1) * 64 + lane) * 8);

#pragma unroll
    for (int sub = 0; sub < 4; ++sub) {
      if (sub < 3) {
        const int Sn = S0 + sub + 1;
        kA[sub + 1][0].u = *reinterpret_cast<const u32x4*>(kfh + ((size_t)(Sn * 2 + 0) * 64 + lane) * 8);
        kA[sub + 1][1].u = *reinterpret_cast<const u32x4*>(kfh + ((size_t)(Sn * 2 + 1) * 64 + lane) * 8);
        vA[sub + 1][0].u = *reinterpret_cast<const u32x4*>(vfh + ((size_t)(Sn * 2 + 0) * 64 + lane) * 8);
        vA[sub + 1][1].u = *reinterpret_cast<const u32x4*>(vfh + ((size_t)(Sn * 2 + 1) * 64 + lane) * 8);
      }
      __builtin_amdgcn_sched_barrier(0);  // pin: prefetch stays issued ahead of compute

      // accumulator init = adj * log2e (replaces zero-init + post-MFMA fma)
      f32x16 c;
#pragma unroll
      for (int G = 0; G < 4; ++G) {
        const f32x4 av = *reinterpret_cast<const f32x4*>(&buf[l31 * 132 + sub * 32 + G * 8 + hi * 4]);
#pragma unroll
        for (int r = 0; r < 4; ++r) c[G * 4 + r] = av[r] * LOG2E;
      }

      f32x16 s = __builtin_amdgcn_mfma_f32_32x32x16_bf16(kA[sub][0].b, qb[0].b, c, 0, 0, 0);
      s = __builtin_amdgcn_mfma_f32_32x32x16_bf16(kA[sub][1].b, qb[1].b, s, 0, 0, 0);

      // p = exp2(s), accumulate row-sum
#pragma unroll
      for (int i = 0; i < 16; ++i) {
        const float p = __builtin_amdgcn_exp2f(s[i]);
        s[i] = p;
        lrun += p;
      }

      // pack P -> bf16 words; permlane32_swap fills both halves with zero selects
      unsigned Pw[4][2];
#pragma unroll
      for (int G = 0; G < 4; ++G) {
        Pw[G][0] = pack2(s[4 * G], s[4 * G + 1]);
        Pw[G][1] = pack2(s[4 * G + 2], s[4 * G + 3]);
      }
      U16x8 pb[2];
#pragma unroll
      for (int kb2 = 0; kb2 < 2; ++kb2)
#pragma unroll
        for (int p = 0; p < 2; ++p) {
          u32x2 r = __builtin_amdgcn_permlane32_swap(Pw[2 * kb2][p], Pw[2 * kb2 + 1][p], false, false);
          pb[kb2].u[p] = r[0];
          pb[kb2].u[2 + p] = r[1];
        }

      o = __builtin_amdgcn_mfma_f32_32x32x16_bf16(vA[sub][0].b, pb[0].b, o, 0, 0, 0);
      o = __builtin_amdgcn_mfma_f32_32x32x16_bf16(vA[sub][1].b, pb[1].b, o, 0, 0, 0);
    }

    // all LDS reads of this buffer done; then DMA-overwrite it with stage t+2
    asm volatile("s_waitcnt lgkmcnt(0)" ::: "memory");
    __builtin_amdgcn_s_barrier();
    __builtin_amdgcn_sched_barrier(0);
    if (t + 2 < 8) {
      float* nb = adj_lds[kvh][t & 1];
#pragma unroll
      for (int r = 0; r < 4; ++r)
#pragma unroll
        for (int half = 0; half < 2; ++half)
          __builtin_amdgcn_global_load_lds(
              (const __attribute__((address_space(1))) unsigned int*)(agbase + (size_t)r * 2048 + (t + 2) * 128 + half * 64),
              (__attribute__((address_space(3))) unsigned int*)(nb + (4 * h + r) * 132 + half * 64),
              4, 0, 0);
    }
  }

  // ---- merge the two KV halves (plain sums; softmax had no max shift) ----
  float l_half = lrun + __shfl_xor(lrun, 32);

  float* mo = &adj_lds[0][0][0];            // overlay: [8][32][36] f32 (36864 B < 67584)
  float* ml = mo + 8 * 32 * 36;             // [8][32]

  __syncthreads();
  if (kvh == 1) {
#pragma unroll
    for (int G = 0; G < 4; ++G) {
      f32x4 v4;
#pragma unroll
      for (int r = 0; r < 4; ++r) v4[r] = o[4 * G + r];
      *reinterpret_cast<f32x4*>(&mo[(h * 32 + l31) * 36 + G * 8 + hi * 4]) = v4;
    }
    if (hi == 0) ml[h * 32 + l31] = l_half;
  }
  __syncthreads();
  if (kvh == 0) {
    const float linv = 1.0f / (l_half + ml[h * 32 + l31]);
#pragma unroll
    for (int G = 0; G < 4; ++G) {
      const f32x4 o1 = *reinterpret_cast<const f32x4*>(&mo[(h * 32 + l31) * 36 + G * 8 + hi * 4]);
      ushort4 st;
      st.x = f2bf((o[4 * G + 0] + o1[0]) * linv);
      st.y = f2bf((o[4 * G + 1] + o1[1]) * linv);
      st.z = f2bf((o[4 * G + 2] + o1[2]) * linv);
      st.w = f2bf((o[4 * G + 3] + o1[3]) * linv);
      *reinterpret_cast<ushort4*>(out + (size_t)(b * 2048 + q0 + l31) * 256 + h * 32 + G * 8 + hi * 4) = st;
    }
  }
}

extern "C" void kernel_launch(void* const* d_in, const int* in_sizes, int n_in,
                              void* d_out, int out_size, void* d_ws, size_t ws_size,
                              hipStream_t stream) {
  const float* h_in  = (const float*)d_in[0];
  const float* adj   = (const float*)d_in[1];
  const float* Wqkv  = (const float*)d_in[2];
  const float* bqkv  = (const float*)d_in[3];
  const float* Wout  = (const float*)d_in[4];
  const float* bout  = (const float*)d_in[5];
  const float* g1    = (const float*)d_in[6];
  const float* beta1 = (const float*)d_in[7];
  const float* g2    = (const float*)d_in[8];
  const float* beta2 = (const float*)d_in[9];
  const float* Wf1   = (const float*)d_in[10];
  const float* bf1   = (const float*)d_in[11];
  const float* Wf2   = (const float*)d_in[12];
  const float* bf2   = (const float*)d_in[13];

  char* ws = (char*)d_ws;
  unsigned short* wqkv_t = (unsigned short*)(ws);                     // 393216 B
  unsigned short* wout_t = (unsigned short*)(ws + 393216);            // 131072
  unsigned short* wf1_t  = (unsigned short*)(ws + 524288);            // 262144
  unsigned short* wf2_t  = (unsigned short*)(ws + 786432);            // 262144
  float*          bqkv_s = (float*)(ws + 1048576);                    // 3072 (pad 4096)
  size_t off = 1052672;
  unsigned short* h_n    = (unsigned short*)(ws + off); off += (size_t)8192 * 256 * 2;
  unsigned short* qbuf   = (unsigned short*)(ws + off); off += (size_t)8192 * 256 * 2;
  unsigned short* kfb    = (unsigned short*)(ws + off); off += (size_t)4 * 8 * 64 * 2 * 64 * 16;
  unsigned short* vfb    = (unsigned short*)(ws + off); off += (size_t)4 * 8 * 64 * 2 * 64 * 16;
  unsigned short* attn_o = (unsigned short*)(ws + off); off += (size_t)8192 * 256 * 2;
  float*          h_mid  = (float*)(ws + off);          off += (size_t)8192 * 256 * 4;
  unsigned short* h2     = (unsigned short*)(ws + off); off += (size_t)8192 * 256 * 2;
  unsigned short* a1     = (unsigned short*)(ws + off); off += (size_t)8192 * 512 * 2;

  prep_ln_kernel<<<4099, 256, 0, stream>>>(Wqkv, Wout, Wf1, Wf2, bqkv,
                                           h_in, g1, beta1,
                                           wqkv_t, wout_t, wf1_t, wf2_t, bqkv_s, h_n);
  qkv_gemm<<<dim3(64, 12), 256, 0, stream>>>(h_n, wqkv_t, bqkv_s, qbuf, kfb, vfb);
  attn_kernel<<<dim3(64, 4), 1024, 0, stream>>>(qbuf, kfb, vfb, adj, attn_o);
  gemm_kernel<1, 256, 256><<<dim3(64, 4), 256, 0, stream>>>(attn_o, wout_t, bout, h_in, h_mid);
  ln_kernel<<<2048, 256, 0, stream>>>(h_mid, g2, beta2, h2);
  gemm_kernel<2, 256, 512><<<dim3(64, 8), 256, 0, stream>>>(h2, wf1_t, bf1, nullptr, a1);
  gemm_kernel<1, 512, 256><<<dim3(64, 4), 256, 0, stream>>>(a1, wf2_t, bf2, h_mid, (float*)d_out);
}

// Round 18
// 121.674 us; speedup vs baseline: 1.0238x; 1.0238x over previous
//
#include <hip/hip_runtime.h>
#include <hip/hip_bf16.h>
#include <cstdint>
#include <cstddef>

typedef __bf16 bf16x8 __attribute__((ext_vector_type(8)));
typedef float f32x4 __attribute__((ext_vector_type(4)));
typedef float f32x16 __attribute__((ext_vector_type(16)));
typedef unsigned int u32x4 __attribute__((ext_vector_type(4)));
typedef unsigned int u32x2 __attribute__((ext_vector_type(2)));

#define SCALE_LOG2E 0.25503513f   // (1/sqrt(32)) * log2(e)
#define LOG2E 1.4426950408889634f

union U16x8 {
  u32x4 u;
  bf16x8 b;
  unsigned short s[8];
  ushort4 q[2];
};

__device__ __forceinline__ unsigned short f2bf(float f) {
  union { float f; unsigned u; } v;
  v.f = f;
  unsigned r = v.u + 0x7FFFu + ((v.u >> 16) & 1u);
  return (unsigned short)(r >> 16);
}

__device__ __forceinline__ unsigned pack2(float a, float b) {
  __hip_bfloat162 t = __float22bfloat162_rn(make_float2(a, b));
  return *reinterpret_cast<unsigned*>(&t);  // low16 = bf(a), high16 = bf(b)
}

// ---------------- merged: weight prep (blocks 0..2050) + LayerNorm1 (blocks 2051..4098) ----------------
__global__ __launch_bounds__(256) void prep_ln_kernel(
    const float* __restrict__ Wqkv, const float* __restrict__ Wout,
    const float* __restrict__ Wf1, const float* __restrict__ Wf2,
    const float* __restrict__ bqkv,
    const float* __restrict__ x, const float* __restrict__ gw, const float* __restrict__ bw,
    unsigned short* __restrict__ qkv_t, unsigned short* __restrict__ out_t,
    unsigned short* __restrict__ f1_t, unsigned short* __restrict__ f2_t,
    float* __restrict__ bqkv_s, unsigned short* __restrict__ ln_out) {
  const int blk = blockIdx.x;
  if (blk >= 2051) {
    const int row = (blk - 2051) * 4 + (threadIdx.x >> 6);
    const int lane = threadIdx.x & 63;
    const float4 v = *reinterpret_cast<const float4*>(x + (size_t)row * 256 + lane * 4);
    float s = v.x + v.y + v.z + v.w;
    float s2 = v.x * v.x + v.y * v.y + v.z * v.z + v.w * v.w;
#pragma unroll
    for (int m = 1; m < 64; m <<= 1) {
      s += __shfl_xor(s, m);
      s2 += __shfl_xor(s2, m);
    }
    const float mean = s * (1.f / 256.f);
    const float var = s2 * (1.f / 256.f) - mean * mean;
    const float rstd = rsqrtf(var + 1e-5f);
    const float4 gg = *reinterpret_cast<const float4*>(gw + lane * 4);
    const float4 bb = *reinterpret_cast<const float4*>(bw + lane * 4);
    ushort4 o;
    o.x = f2bf((v.x - mean) * rstd * gg.x + bb.x);
    o.y = f2bf((v.y - mean) * rstd * gg.y + bb.y);
    o.z = f2bf((v.z - mean) * rstd * gg.z + bb.z);
    o.w = f2bf((v.w - mean) * rstd * gg.w + bb.w);
    *reinterpret_cast<ushort4*>(ln_out + (size_t)row * 256 + lane * 4) = o;
    return;
  }
  int i = blk * 256 + threadIdx.x;
  if (i < 768 * 256) {
    int n = i >> 8, k = i & 255;
    float v = Wqkv[k * 768 + n];
    if (n < 256) v *= SCALE_LOG2E;  // fold softmax scale * log2e into Q
    qkv_t[i] = f2bf(v);
    return;
  }
  i -= 768 * 256;
  if (i < 256 * 256) { int n = i >> 8, k = i & 255; out_t[i] = f2bf(Wout[k * 256 + n]); return; }
  i -= 256 * 256;
  if (i < 512 * 256) { int n = i >> 8, k = i & 255; f1_t[i] = f2bf(Wf1[k * 512 + n]); return; }
  i -= 512 * 256;
  if (i < 256 * 512) { int n = i >> 9, k = i & 511; f2_t[i] = f2bf(Wf2[k * 256 + n]); return; }
  i -= 256 * 512;
  if (i < 768) bqkv_s[i] = bqkv[i] * (i < 256 ? SCALE_LOG2E : 1.0f);
}

// ---------------- LayerNorm (f32 in -> bf16 out), 1 wave per 256-wide row ----------------
__global__ __launch_bounds__(256) void ln_kernel(
    const float* __restrict__ x, const float* __restrict__ gw, const float* __restrict__ bw,
    unsigned short* __restrict__ out) {
  const int row = blockIdx.x * 4 + (threadIdx.x >> 6);
  const int lane = threadIdx.x & 63;
  const float4 v = *reinterpret_cast<const float4*>(x + (size_t)row * 256 + lane * 4);
  float s = v.x + v.y + v.z + v.w;
  float s2 = v.x * v.x + v.y * v.y + v.z * v.z + v.w * v.w;
#pragma unroll
  for (int m = 1; m < 64; m <<= 1) {
    s += __shfl_xor(s, m);
    s2 += __shfl_xor(s2, m);
  }
  const float mean = s * (1.f / 256.f);
  const float var = s2 * (1.f / 256.f) - mean * mean;
  const float rstd = rsqrtf(var + 1e-5f);
  const float4 gg = *reinterpret_cast<const float4*>(gw + lane * 4);
  const float4 bb = *reinterpret_cast<const float4*>(bw + lane * 4);
  ushort4 o;
  o.x = f2bf((v.x - mean) * rstd * gg.x + bb.x);
  o.y = f2bf((v.y - mean) * rstd * gg.y + bb.y);
  o.z = f2bf((v.z - mean) * rstd * gg.z + bb.z);
  o.w = f2bf((v.w - mean) * rstd * gg.w + bb.w);
  *reinterpret_cast<ushort4*>(out + (size_t)row * 256 + lane * 4) = o;
}

// ---------------- direct-global MFMA GEMM, 128x64 tile, pinned 1-ahead prefetch ----------------
template <int EPI, int K, int N>
__global__ __launch_bounds__(256) void gemm_kernel(
    const unsigned short* __restrict__ A, const unsigned short* __restrict__ Wt,
    const float* __restrict__ bias, const float* __restrict__ res, void* __restrict__ outp) {
  const int w = threadIdx.x >> 6;
  const int lane = threadIdx.x & 63;
  const int l15 = lane & 15;
  const int g = lane >> 4;
  const int m0 = blockIdx.x * 128 + w * 32;
  const int n0 = blockIdx.y * 64;
  constexpr int KI = K / 32;

  const unsigned short* a0p = A + (size_t)(m0 + l15) * K + g * 8;
  const unsigned short* a1p = A + (size_t)(m0 + 16 + l15) * K + g * 8;
  const unsigned short* wp = Wt + (size_t)(n0 + l15) * K + g * 8;

  f32x4 acc[2][4];
#pragma unroll
  for (int mf = 0; mf < 2; ++mf)
#pragma unroll
    for (int nf = 0; nf < 4; ++nf) acc[mf][nf] = f32x4{0.f, 0.f, 0.f, 0.f};

  U16x8 a[2][2], bfr[2][4];

#define GEMM_LOAD(kk, buf)                                                                  \
  do {                                                                                      \
    a[buf][0].u = *reinterpret_cast<const u32x4*>(a0p + (kk) * 32);                         \
    a[buf][1].u = *reinterpret_cast<const u32x4*>(a1p + (kk) * 32);                         \
    bfr[buf][0].u = *reinterpret_cast<const u32x4*>(wp + (size_t)0 * 16 * K + (kk) * 32);   \
    bfr[buf][1].u = *reinterpret_cast<const u32x4*>(wp + (size_t)1 * 16 * K + (kk) * 32);   \
    bfr[buf][2].u = *reinterpret_cast<const u32x4*>(wp + (size_t)2 * 16 * K + (kk) * 32);   \
    bfr[buf][3].u = *reinterpret_cast<const u32x4*>(wp + (size_t)3 * 16 * K + (kk) * 32);   \
  } while (0)

  GEMM_LOAD(0, 0);
  __builtin_amdgcn_sched_barrier(0);

#pragma unroll
  for (int kk = 0; kk < KI; ++kk) {
    if (kk + 1 < KI) GEMM_LOAD(kk + 1, (kk + 1) & 1);
    __builtin_amdgcn_sched_barrier(0);
    const int buf = kk & 1;
#pragma unroll
    for (int mf = 0; mf < 2; ++mf)
#pragma unroll
      for (int nf = 0; nf < 4; ++nf)
        acc[mf][nf] = __builtin_amdgcn_mfma_f32_16x16x32_bf16(a[buf][mf].b, bfr[buf][nf].b, acc[mf][nf], 0, 0, 0);
  }
#undef GEMM_LOAD

#pragma unroll
  for (int mf = 0; mf < 2; ++mf)
#pragma unroll
    for (int nf = 0; nf < 4; ++nf)
#pragma unroll
      for (int r = 0; r < 4; ++r) {
        const int m = m0 + mf * 16 + g * 4 + r;
        const int n = n0 + nf * 16 + l15;
        float v = acc[mf][nf][r] + bias[n];
        if constexpr (EPI == 1) {
          v += res[(size_t)m * 256 + n];
          reinterpret_cast<float*>(outp)[(size_t)m * 256 + n] = v;
        } else if constexpr (EPI == 2) {
          v = 0.5f * v * (1.0f + erff(v * 0.70710678118654752f));
          reinterpret_cast<unsigned short*>(outp)[(size_t)m * N + n] = f2bf(v);
        } else {
          reinterpret_cast<unsigned short*>(outp)[(size_t)m * N + n] = f2bf(v);
        }
      }
}

// ---------------- fused QKV GEMM: Q -> qbuf[c][256], K/V -> frag-contiguous kf/vf ----------------
__global__ __launch_bounds__(256) void qkv_gemm(
    const unsigned short* __restrict__ A, const unsigned short* __restrict__ Wt,
    const float* __restrict__ bias,
    unsigned short* __restrict__ qbuf, unsigned short* __restrict__ kf,
    unsigned short* __restrict__ vf) {
  __shared__ unsigned short tile[128][72];  // row stride 144 B (16B-aligned rows)
  const int w = threadIdx.x >> 6;
  const int lane = threadIdx.x & 63;
  const int l15 = lane & 15, g = lane >> 4;
  const int l31 = lane & 31, hi = lane >> 5;
  const int mb = blockIdx.x, nb = blockIdx.y;
  const int m0 = mb * 128 + w * 32;
  const int n0 = nb * 64;
  constexpr int K = 256;
  constexpr int KI = 8;

  const unsigned short* a0p = A + (size_t)(m0 + l15) * K + g * 8;
  const unsigned short* a1p = A + (size_t)(m0 + 16 + l15) * K + g * 8;
  const unsigned short* wp = Wt + (size_t)(n0 + l15) * K + g * 8;

  f32x4 acc[2][4];
#pragma unroll
  for (int mf = 0; mf < 2; ++mf)
#pragma unroll
    for (int nf = 0; nf < 4; ++nf) acc[mf][nf] = f32x4{0.f, 0.f, 0.f, 0.f};

  U16x8 a[2][2], bfr[2][4];

#define QKV_LOAD(kk, buf)                                                                   \
  do {                                                                                      \
    a[buf][0].u = *reinterpret_cast<const u32x4*>(a0p + (kk) * 32);                         \
    a[buf][1].u = *reinterpret_cast<const u32x4*>(a1p + (kk) * 32);                         \
    bfr[buf][0].u = *reinterpret_cast<const u32x4*>(wp + (size_t)0 * 16 * K + (kk) * 32);   \
    bfr[buf][1].u = *reinterpret_cast<const u32x4*>(wp + (size_t)1 * 16 * K + (kk) * 32);   \
    bfr[buf][2].u = *reinterpret_cast<const u32x4*>(wp + (size_t)2 * 16 * K + (kk) * 32);   \
    bfr[buf][3].u = *reinterpret_cast<const u32x4*>(wp + (size_t)3 * 16 * K + (kk) * 32);   \
  } while (0)

  QKV_LOAD(0, 0);
  __builtin_amdgcn_sched_barrier(0);

#pragma unroll
  for (int kk = 0; kk < KI; ++kk) {
    if (kk + 1 < KI) QKV_LOAD(kk + 1, (kk + 1) & 1);
    __builtin_amdgcn_sched_barrier(0);
    const int buf = kk & 1;
#pragma unroll
    for (int mf = 0; mf < 2; ++mf)
#pragma unroll
      for (int nf = 0; nf < 4; ++nf)
        acc[mf][nf] = __builtin_amdgcn_mfma_f32_16x16x32_bf16(a[buf][mf].b, bfr[buf][nf].b, acc[mf][nf], 0, 0, 0);
  }
#undef QKV_LOAD

  if (nb < 4) {
    // Q region: row-major qbuf [8192][256]
#pragma unroll
    for (int mf = 0; mf < 2; ++mf)
#pragma unroll
      for (int nf = 0; nf < 4; ++nf)
#pragma unroll
        for (int r = 0; r < 4; ++r) {
          const int m = m0 + mf * 16 + g * 4 + r;
          const int n = n0 + nf * 16 + l15;
          qbuf[(size_t)m * 256 + n] = f2bf(acc[mf][nf][r] + bias[n]);
        }
    return;
  }

  // K/V region: stage bf16 tile [c_local][n_local] in LDS
#pragma unroll
  for (int mf = 0; mf < 2; ++mf)
#pragma unroll
    for (int nf = 0; nf < 4; ++nf)
#pragma unroll
      for (int r = 0; r < 4; ++r) {
        const int n = n0 + nf * 16 + l15;
        tile[w * 32 + mf * 16 + g * 4 + r][nf * 16 + l15] = f2bf(acc[mf][nf][r] + bias[n]);
      }
  __syncthreads();

  const int b = mb >> 4;
  const int Sg = (mb & 15) * 4 + w;  // wave w owns c-subtile w of this 128-row tile

  if (nb < 8) {
    // K: kf chunk (b,h,Sg,d2)[lane]: K[c=Sg*32+l31][dk=d2*16+hi*8+j]
    const int hb = 2 * (nb - 4);
#pragma unroll
    for (int hd2 = 0; hd2 < 4; ++hd2) {
      const int hl = hd2 >> 1, d2 = hd2 & 1;
      U16x8 vv;
      vv.q[0] = *reinterpret_cast<const ushort4*>(&tile[w * 32 + l31][hl * 32 + d2 * 16 + hi * 8]);
      vv.q[1] = *reinterpret_cast<const ushort4*>(&tile[w * 32 + l31][hl * 32 + d2 * 16 + hi * 8 + 4]);
      const size_t chunk = ((size_t)(b * 8 + hb + hl) * 64 + Sg) * 2 + d2;
      *reinterpret_cast<u32x4*>(kf + chunk * 512 + lane * 8) = vv.u;
    }
  } else {
    // V: vf chunk (b,h,Sg,kd2)[lane]: V[c=Sg*32+kd2*16+hi*8+j][d=l31] (transpose read)
    const int hb = 2 * (nb - 8);
#pragma unroll
    for (int hd2 = 0; hd2 < 4; ++hd2) {
      const int hl = hd2 >> 1, kd2 = hd2 & 1;
      U16x8 vv;
#pragma unroll
      for (int j = 0; j < 8; ++j)
        vv.s[j] = tile[w * 32 + kd2 * 16 + hi * 8 + j][hl * 32 + l31];
      const size_t chunk = ((size_t)(b * 8 + hb + hl) * 64 + Sg) * 2 + kd2;
      *reinterpret_cast<u32x4*>(vf + chunk * 512 + lane * 8) = vv.u;
    }
  }
}

// ---------------- flash attention (R13 structure: 3-buffer DMA adj, per-sub pinned pipeline) ----------------
// 16 waves = 8 heads x 2 KV-halves. S^T[k][q] = mfma32(K, Q^T), exp2 softmax (no max
// tracking; scores bounded), P exchange via permlane32_swap, O^T += mfma32(V^T, P).
// K/V frags pinned ONE sub ahead with sched_barrier(0): only 2 sub-buffers live at once
// (64 VGPR measured). Session-final configuration: measured 54.8 us attn / 121.9 us total.
__global__ __launch_bounds__(1024) void attn_kernel(
    const unsigned short* __restrict__ qbuf,
    const unsigned short* __restrict__ kf, const unsigned short* __restrict__ vf,
    const float* __restrict__ adj, unsigned short* __restrict__ out) {
  __shared__ __align__(16) float adj_lds[2][3][32 * 132];  // 101376 B
  const int w = threadIdx.x >> 6;
  const int lane = threadIdx.x & 63;
  const int l31 = lane & 31;
  const int hi = lane >> 5;
  const int h = w & 7;
  const int kvh = w >> 3;
  const int q0 = blockIdx.x * 32;
  const int b = blockIdx.y;

  const float* agbase = adj + (size_t)(b * 2048 + q0 + 4 * h) * 2048 + kvh * 1024 + lane;

  // Q B-frags (persistent, pre-scaled by scale*log2e): B[kk=hi*8+j][q=l31]
  U16x8 qb[2];
#pragma unroll
  for (int d = 0; d < 2; ++d)
    qb[d].u = *reinterpret_cast<const u32x4*>(
        qbuf + (size_t)(b * 2048 + q0 + l31) * 256 + h * 32 + d * 16 + hi * 8);

  const unsigned short* kfh = kf + (size_t)(b * 8 + h) * 65536;
  const unsigned short* vfh = vf + (size_t)(b * 8 + h) * 65536;

  f32x16 o;
#pragma unroll
  for (int i = 0; i < 16; ++i) o[i] = 0.f;
  float lrun = 0.f;

  // prologue: DMA adj tiles 0,1,2 (8 dword-DMAs per wave per tile)
#pragma unroll
  for (int pt = 0; pt < 3; ++pt)
#pragma unroll
    for (int r = 0; r < 4; ++r)
#pragma unroll
      for (int half = 0; half < 2; ++half)
        __builtin_amdgcn_global_load_lds(
            (const __attribute__((address_space(1))) unsigned int*)(agbase + (size_t)r * 2048 + pt * 128 + half * 64),
            (__attribute__((address_space(3))) unsigned int*)(&adj_lds[kvh][pt][(4 * h + r) * 132 + half * 64]),
            4, 0, 0);

#pragma unroll 1
  for (int t = 0; t < 8; ++t) {
    const float* buf = adj_lds[kvh][t % 3];
    if (t < 6)       asm volatile("s_waitcnt vmcnt(16)" ::: "memory");
    else if (t == 6) asm volatile("s_waitcnt vmcnt(8)" ::: "memory");
    else             asm volatile("s_waitcnt vmcnt(0)" ::: "memory");
    __builtin_amdgcn_s_barrier();
    __builtin_amdgcn_sched_barrier(0);

    const int S0 = kvh * 32 + t * 4;  // first 32-kv subtile of this tile

    // K/V frags, software-pipelined one sub ahead (full unroll -> static indices)
    U16x8 kA[4][2], vA[4][2];
    kA[0][0].u = *reinterpret_cast<const u32x4*>(kfh + ((size_t)(S0 * 2 + 0) * 64 + lane) * 8);
    kA[0][1].u = *reinterpret_cast<const u32x4*>(kfh + ((size_t)(S0 * 2 + 1) * 64 + lane) * 8);
    vA[0][0].u = *reinterpret_cast<const u32x4*>(vfh + ((size_t)(S0 * 2 + 0) * 64 + lane) * 8);
    vA[0][1].u = *reinterpret_cast<const u32x4*>(vfh + ((size_t)(S0 * 2 + 1) * 64 + lane) * 8);

#pragma unroll
    for (int sub = 0; sub < 4; ++sub) {
      if (sub < 3) {
        const int Sn = S0 + sub + 1;
        kA[sub + 1][0].u = *reinterpret_cast<const u32x4*>(kfh + ((size_t)(Sn * 2 + 0) * 64 + lane) * 8);
        kA[sub + 1][1].u = *reinterpret_cast<const u32x4*>(kfh + ((size_t)(Sn * 2 + 1) * 64 + lane) * 8);
        vA[sub + 1][0].u = *reinterpret_cast<const u32x4*>(vfh + ((size_t)(Sn * 2 + 0) * 64 + lane) * 8);
        vA[sub + 1][1].u = *reinterpret_cast<const u32x4*>(vfh + ((size_t)(Sn * 2 + 1) * 64 + lane) * 8);
      }
      __builtin_amdgcn_sched_barrier(0);  // pin: prefetch stays issued ahead of compute

      // accumulator init = adj * log2e (replaces zero-init + post-MFMA fma)
      f32x16 c;
#pragma unroll
      for (int G = 0; G < 4; ++G) {
        const f32x4 av = *reinterpret_cast<const f32x4*>(&buf[l31 * 132 + sub * 32 + G * 8 + hi * 4]);
#pragma unroll
        for (int r = 0; r < 4; ++r) c[G * 4 + r] = av[r] * LOG2E;
      }

      f32x16 s = __builtin_amdgcn_mfma_f32_32x32x16_bf16(kA[sub][0].b, qb[0].b, c, 0, 0, 0);
      s = __builtin_amdgcn_mfma_f32_32x32x16_bf16(kA[sub][1].b, qb[1].b, s, 0, 0, 0);

      // p = exp2(s), accumulate row-sum
#pragma unroll
      for (int i = 0; i < 16; ++i) {
        const float p = __builtin_amdgcn_exp2f(s[i]);
        s[i] = p;
        lrun += p;
      }

      // pack P -> bf16 words; permlane32_swap fills both halves with zero selects
      unsigned Pw[4][2];
#pragma unroll
      for (int G = 0; G < 4; ++G) {
        Pw[G][0] = pack2(s[4 * G], s[4 * G + 1]);
        Pw[G][1] = pack2(s[4 * G + 2], s[4 * G + 3]);
      }
      U16x8 pb[2];
#pragma unroll
      for (int kb2 = 0; kb2 < 2; ++kb2)
#pragma unroll
        for (int p = 0; p < 2; ++p) {
          u32x2 r = __builtin_amdgcn_permlane32_swap(Pw[2 * kb2][p], Pw[2 * kb2 + 1][p], false, false);
          pb[kb2].u[p] = r[0];
          pb[kb2].u[2 + p] = r[1];
        }

      o = __builtin_amdgcn_mfma_f32_32x32x16_bf16(vA[sub][0].b, pb[0].b, o, 0, 0, 0);
      o = __builtin_amdgcn_mfma_f32_32x32x16_bf16(vA[sub][1].b, pb[1].b, o, 0, 0, 0);
    }

    // all LDS reads of this buffer done; then DMA-overwrite it with tile t+3
    asm volatile("s_waitcnt lgkmcnt(0)" ::: "memory");
    __builtin_amdgcn_s_barrier();
    __builtin_amdgcn_sched_barrier(0);
    if (t + 3 < 8) {
      float* nb = adj_lds[kvh][t % 3];
#pragma unroll
      for (int r = 0; r < 4; ++r)
#pragma unroll
        for (int half = 0; half < 2; ++half)
          __builtin_amdgcn_global_load_lds(
              (const __attribute__((address_space(1))) unsigned int*)(agbase + (size_t)r * 2048 + (t + 3) * 128 + half * 64),
              (__attribute__((address_space(3))) unsigned int*)(nb + (4 * h + r) * 132 + half * 64),
              4, 0, 0);
    }
  }

  // ---- merge the two KV halves (plain sums; softmax had no max shift) ----
  float l_half = lrun + __shfl_xor(lrun, 32);

  float* mo = &adj_lds[0][0][0];            // overlay: [8][32][36] f32
  float* ml = mo + 8 * 32 * 36;             // [8][32]

  __syncthreads();
  if (kvh == 1) {
#pragma unroll
    for (int G = 0; G < 4; ++G) {
      f32x4 v4;
#pragma unroll
      for (int r = 0; r < 4; ++r) v4[r] = o[4 * G + r];
      *reinterpret_cast<f32x4*>(&mo[(h * 32 + l31) * 36 + G * 8 + hi * 4]) = v4;
    }
    if (hi == 0) ml[h * 32 + l31] = l_half;
  }
  __syncthreads();
  if (kvh == 0) {
    const float linv = 1.0f / (l_half + ml[h * 32 + l31]);
#pragma unroll
    for (int G = 0; G < 4; ++G) {
      const f32x4 o1 = *reinterpret_cast<const f32x4*>(&mo[(h * 32 + l31) * 36 + G * 8 + hi * 4]);
      ushort4 st;
      st.x = f2bf((o[4 * G + 0] + o1[0]) * linv);
      st.y = f2bf((o[4 * G + 1] + o1[1]) * linv);
      st.z = f2bf((o[4 * G + 2] + o1[2]) * linv);
      st.w = f2bf((o[4 * G + 3] + o1[3]) * linv);
      *reinterpret_cast<ushort4*>(out + (size_t)(b * 2048 + q0 + l31) * 256 + h * 32 + G * 8 + hi * 4) = st;
    }
  }
}

extern "C" void kernel_launch(void* const* d_in, const int* in_sizes, int n_in,
                              void* d_out, int out_size, void* d_ws, size_t ws_size,
                              hipStream_t stream) {
  const float* h_in  = (const float*)d_in[0];
  const float* adj   = (const float*)d_in[1];
  const float* Wqkv  = (const float*)d_in[2];
  const float* bqkv  = (const float*)d_in[3];
  const float* Wout  = (const float*)d_in[4];
  const float* bout  = (const float*)d_in[5];
  const float* g1    = (const float*)d_in[6];
  const float* beta1 = (const float*)d_in[7];
  const float* g2    = (const float*)d_in[8];
  const float* beta2 = (const float*)d_in[9];
  const float* Wf1   = (const float*)d_in[10];
  const float* bf1   = (const float*)d_in[11];
  const float* Wf2   = (const float*)d_in[12];
  const float* bf2   = (const float*)d_in[13];

  char* ws = (char*)d_ws;
  unsigned short* wqkv_t = (unsigned short*)(ws);                     // 393216 B
  unsigned short* wout_t = (unsigned short*)(ws + 393216);            // 131072
  unsigned short* wf1_t  = (unsigned short*)(ws + 524288);            // 262144
  unsigned short* wf2_t  = (unsigned short*)(ws + 786432);            // 262144
  float*          bqkv_s = (float*)(ws + 1048576);                    // 3072 (pad 4096)
  size_t off = 1052672;
  unsigned short* h_n    = (unsigned short*)(ws + off); off += (size_t)8192 * 256 * 2;
  unsigned short* qbuf   = (unsigned short*)(ws + off); off += (size_t)8192 * 256 * 2;
  unsigned short* kfb    = (unsigned short*)(ws + off); off += (size_t)4 * 8 * 64 * 2 * 64 * 16;
  unsigned short* vfb    = (unsigned short*)(ws + off); off += (size_t)4 * 8 * 64 * 2 * 64 * 16;
  unsigned short* attn_o = (unsigned short*)(ws + off); off += (size_t)8192 * 256 * 2;
  float*          h_mid  = (float*)(ws + off);          off += (size_t)8192 * 256 * 4;
  unsigned short* h2     = (unsigned short*)(ws + off); off += (size_t)8192 * 256 * 2;
  unsigned short* a1     = (unsigned short*)(ws + off); off += (size_t)8192 * 512 * 2;

  prep_ln_kernel<<<4099, 256, 0, stream>>>(Wqkv, Wout, Wf1, Wf2, bqkv,
                                           h_in, g1, beta1,
                                           wqkv_t, wout_t, wf1_t, wf2_t, bqkv_s, h_n);
  qkv_gemm<<<dim3(64, 12), 256, 0, stream>>>(h_n, wqkv_t, bqkv_s, qbuf, kfb, vfb);
  attn_kernel<<<dim3(64, 4), 1024, 0, stream>>>(qbuf, kfb, vfb, adj, attn_o);
  gemm_kernel<1, 256, 256><<<dim3(64, 4), 256, 0, stream>>>(attn_o, wout_t, bout, h_in, h_mid);
  ln_kernel<<<2048, 256, 0, stream>>>(h_mid, g2, beta2, h2);
  gemm_kernel<2, 256, 512><<<dim3(64, 8), 256, 0, stream>>>(h2, wf1_t, bf1, nullptr, a1);
  gemm_kernel<1, 512, 256><<<dim3(64, 4), 256, 0, stream>>>(a1, wf2_t, bf2, h_mid, (float*)d_out);
}